// Round 18
// baseline (354.102 us; speedup 1.0000x reference)
//
#include <hip/hip_runtime.h>
#include <cstdint>
#include <cstddef>

typedef _Float16 half_t;
typedef _Float16 half4_t __attribute__((ext_vector_type(4)));
typedef _Float16 half8_t __attribute__((ext_vector_type(8)));
typedef unsigned short ushort8_t __attribute__((ext_vector_type(8)));
typedef float floatx4 __attribute__((ext_vector_type(4)));

#define NROWS 4096
#define DMODEL 1024
#define NLAT 16384
#define CAND_MAX 256

// ---------------- ws layout (bytes) ----------------
#define MBYTE (1ull << 20)
static const size_t oW0    = 0;                           // 32MB fp16 W_enc*1024
static const size_t oWdT   = 32 * MBYTE;                  // 32MB fp16 W_dec^T
static const size_t oMeanD = 64 * MBYTE;                  // 32KB
static const size_t oNormD = 64 * MBYTE + (64ull << 10);  // 32KB
static const size_t oCandC = 64 * MBYTE + (128ull << 10); // 16KB
static const size_t oCandI = 65 * MBYTE;                  // 4096*256*4 = 4MB
static const size_t oBatch = 69 * MBYTE;

// per-row batch bytes: X0 fp16 (2048) + hb fp16 (32768)
#define BATCH_ROW_BYTES 34816ull

// ---------------- helpers ----------------
__device__ __forceinline__ void gload16(const void* g, void* l) {
  __builtin_amdgcn_global_load_lds(
      (const __attribute__((address_space(1))) void*)g,
      (__attribute__((address_space(3))) void*)l, 16, 0, 0);
}

// ---------------- kernel 1: fused preprocessing ----------------
#define WSPLIT_B 2048
#define TRANS_B  4096   // (NLAT/64) * (DMODEL/64)
__global__ __launch_bounds__(256) void prepro_kernel(
    const float* __restrict__ x, const float* __restrict__ b_pre,
    const float* __restrict__ W_enc, const float* __restrict__ Wd,
    half_t* __restrict__ W0h, half_t* __restrict__ WdT,
    half_t* __restrict__ X0,
    double* __restrict__ meanD, double* __restrict__ normD, int r0) {
  int bid = blockIdx.x, tid = threadIdx.x;
  if (bid < WSPLIT_B) {
    size_t base = (size_t)bid * 2048 + tid;
    for (int it = 0; it < 8; ++it) {
      size_t i = base + (size_t)it * 256;
      float4 v = ((const float4*)W_enc)[i];
      half4_t h0;
      h0[0] = (half_t)(v.x * 1024.0f);
      h0[1] = (half_t)(v.y * 1024.0f);
      h0[2] = (half_t)(v.z * 1024.0f);
      h0[3] = (half_t)(v.w * 1024.0f);
      ((half4_t*)W0h)[i] = h0;
    }
    return;
  }
  if (bid < WSPLIT_B + TRANS_B) {
    __shared__ float tile[64][65];
    int t = bid - WSPLIT_B;
    int c0 = (t & 255) * 64;   // over NLAT
    int r0t = (t >> 8) * 64;   // over DMODEL
    int tc = tid & 63, tg = tid >> 6;
    for (int i = 0; i < 16; ++i) {
      int rr = i * 4 + tg;
      tile[rr][tc] = Wd[(size_t)(r0t + rr) * NLAT + c0 + tc];
    }
    __syncthreads();
    for (int i = 0; i < 16; ++i) {
      int cc = i * 4 + tg;
      WdT[(size_t)(c0 + cc) * DMODEL + r0t + tc] = (half_t)tile[tc][cc];
    }
    return;
  }
  int rl = bid - WSPLIT_B - TRANS_B;
  int rg = r0 + rl;
  const float4* px = (const float4*)(x + (size_t)rg * DMODEL);
  float4 v = px[tid];
  double s  = (double)v.x + (double)v.y + (double)v.z + (double)v.w;
  double sq = (double)v.x * v.x + (double)v.y * v.y +
              (double)v.z * v.z + (double)v.w * v.w;
  for (int off = 32; off; off >>= 1) {
    s += __shfl_down(s, off);
    sq += __shfl_down(sq, off);
  }
  __shared__ double ss[4], ssq[4];
  __shared__ double sMean, sNorm;
  int wv = tid >> 6, ln = tid & 63;
  if (ln == 0) { ss[wv] = s; ssq[wv] = sq; }
  __syncthreads();
  if (tid == 0) {
    double S = ss[0] + ss[1] + ss[2] + ss[3];
    double Q = ssq[0] + ssq[1] + ssq[2] + ssq[3];
    double mean = S / (double)DMODEL;
    double var = (Q - (double)DMODEL * mean * mean) / (double)(DMODEL - 1);
    double nrm = sqrt(var) + 1e-6;
    sMean = mean; sNorm = nrm;
    meanD[rg] = mean; normD[rg] = nrm;
  }
  __syncthreads();
  float mean = (float)sMean, nrm = (float)sNorm;
  const float4* pb = (const float4*)b_pre;
  float4 bp = pb[tid];
  float c[4];
  c[0] = ((v.x - mean) / nrm - bp.x) * 1024.0f;
  c[1] = ((v.y - mean) / nrm - bp.y) * 1024.0f;
  c[2] = ((v.z - mean) / nrm - bp.z) * 1024.0f;
  c[3] = ((v.w - mean) / nrm - bp.w) * 1024.0f;
  half4_t h0;
  for (int i = 0; i < 4; ++i) h0[i] = (half_t)c[i];
  ((half4_t*)(X0 + (size_t)rl * DMODEL))[tid] = h0;
}

// ---------------- kernel 2: encode GEMM, 8-phase + one-phase-ahead LDS prefetch ----------------
__global__ __launch_bounds__(512, 2) void gemm_enc(
    const half_t* __restrict__ X0, const half_t* __restrict__ W0,
    const float* __restrict__ b_enc, half_t* __restrict__ h, int mtiles) {
  __shared__ __align__(16) half_t As[2][256 * 64];
  __shared__ __align__(16) half_t Bs[2][256 * 64];
  int tid = threadIdx.x;
  int lane = tid & 63, wave = tid >> 6;
  int wm = wave >> 2, wn = wave & 3;

  int bid = blockIdx.x;
  int xcd = bid & 7, q = bid >> 3;
  int bn = xcd * 8 + (q & 7);
  int bm = q >> 3;
  (void)mtiles;

  const char* Ag = (const char*)(X0 + (size_t)bm * 256 * DMODEL);
  const char* Bg = (const char*)(W0 + (size_t)bn * 256 * DMODEL);

  int srcSwz = ((lane & 7) ^ (lane >> 3)) << 4;
  int rowBase = wave * 8 + (lane >> 3);
  int ldsWOff = wave * 1024;

#define STG_A(b, kt, pr) { int colB = ((kt) & 15) * 128 + srcSwz;             \
    gload16(Ag + (size_t)((pr) * 64 + rowBase) * 2048 + colB,                 \
            (char*)As[b] + (pr) * 8192 + ldsWOff);                            \
    gload16(Ag + (size_t)(((pr) + 2) * 64 + rowBase) * 2048 + colB,           \
            (char*)As[b] + ((pr) + 2) * 8192 + ldsWOff); }
#define STG_B(b, kt, pr) { int colB = ((kt) & 15) * 128 + srcSwz;             \
    gload16(Bg + (size_t)((pr) * 64 + rowBase) * 2048 + colB,                 \
            (char*)Bs[b] + (pr) * 8192 + ldsWOff);                            \
    gload16(Bg + (size_t)(((pr) + 2) * 64 + rowBase) * 2048 + colB,           \
            (char*)Bs[b] + ((pr) + 2) * 8192 + ldsWOff); }

  floatx4 acc[8][4] = {};

  STG_B(0, 0, 0); STG_B(0, 0, 1); STG_A(0, 0, 0); STG_A(0, 0, 1);
  STG_B(1, 1, 0); STG_B(1, 1, 1); STG_A(1, 1, 0);
  asm volatile("s_waitcnt vmcnt(6)" ::: "memory");
  __builtin_amdgcn_sched_barrier(0);
  __builtin_amdgcn_s_barrier();

  int laneQ = (lane & 15) * 128 + (lane >> 4) * 16;
  int sxor = (lane & 7) << 4;
  int aRow = wm * 128 * 128;
  int bRow = wn * 64 * 128;

  half8_t bfr[2][4], afA[4], afB[4];
  const char *Ab, *Bb;

#define LD_B(kk) _Pragma("unroll") for (int t = 0; t < 4; ++t)                \
    bfr[kk][t] = *(const half8_t*)(Bb + ((bRow + t * 2048 +                   \
                                          (kk) * 64 + laneQ) ^ sxor));
#define LD_AF(DST, mh, kk) _Pragma("unroll") for (int t = 0; t < 4; ++t)      \
    DST[t] = *(const half8_t*)(Ab + ((aRow + ((mh) * 4 + t) * 2048 +          \
                                      (kk) * 64 + laneQ) ^ sxor));
#define MM(mb, FR, kk) __builtin_amdgcn_s_setprio(1);                         \
    _Pragma("unroll") for (int mi = 0; mi < 4; ++mi)                          \
    _Pragma("unroll") for (int ni = 0; ni < 4; ++ni)                          \
      acc[(mb) + mi][ni] = __builtin_amdgcn_mfma_f32_16x16x32_f16(            \
          FR[mi], bfr[kk][ni], acc[(mb) + mi][ni], 0, 0, 0);                  \
    __builtin_amdgcn_s_setprio(0);
#define BAR() __builtin_amdgcn_s_barrier()
#define LGKM(n) { asm volatile("s_waitcnt lgkmcnt(" #n ")" ::: "memory");     \
    __builtin_amdgcn_sched_barrier(0); }
#define VM6() { asm volatile("s_waitcnt vmcnt(6)" ::: "memory");              \
    __builtin_amdgcn_sched_barrier(0); }
#define VM0() { asm volatile("s_waitcnt vmcnt(0)" ::: "memory");              \
    __builtin_amdgcn_sched_barrier(0); }

#pragma unroll 1
  for (int i = 0; i < 7; ++i) {
    int t0 = 2 * i;
    Ab = (const char*)As[0]; Bb = (const char*)Bs[0];
    LD_B(0); LD_B(1); LD_AF(afA, 0, 0); LD_AF(afB, 1, 0);
    STG_A(1, t0 + 1, 1);
    BAR(); LGKM(4); MM(0, afA, 0); BAR();
    LD_AF(afA, 0, 1);
    STG_B(0, t0 + 2, 0);
    BAR(); LGKM(4); MM(4, afB, 0); BAR();
    LD_AF(afB, 1, 1);
    STG_B(0, t0 + 2, 1);
    BAR(); LGKM(4); MM(0, afA, 1); BAR();
    STG_A(0, t0 + 2, 0);
    BAR(); LGKM(0); MM(4, afB, 1); VM6(); BAR();
    Ab = (const char*)As[1]; Bb = (const char*)Bs[1];
    LD_B(0); LD_B(1); LD_AF(afA, 0, 0); LD_AF(afB, 1, 0);
    STG_A(0, t0 + 2, 1);
    BAR(); LGKM(4); MM(0, afA, 0); BAR();
    LD_AF(afA, 0, 1);
    STG_B(1, t0 + 3, 0);
    BAR(); LGKM(4); MM(4, afB, 0); BAR();
    LD_AF(afB, 1, 1);
    STG_B(1, t0 + 3, 1);
    BAR(); LGKM(4); MM(0, afA, 1); BAR();
    STG_A(1, t0 + 3, 0);
    BAR(); LGKM(0); MM(4, afB, 1); VM6(); BAR();
  }
  {
    Ab = (const char*)As[0]; Bb = (const char*)Bs[0];
    LD_B(0); LD_B(1); LD_AF(afA, 0, 0); LD_AF(afB, 1, 0);
    STG_A(1, 15, 1);
    BAR(); LGKM(4); MM(0, afA, 0); BAR();
    LD_AF(afA, 0, 1);
    BAR(); LGKM(4); MM(4, afB, 0); BAR();
    LD_AF(afB, 1, 1);
    BAR(); LGKM(4); MM(0, afA, 1); BAR();
    BAR(); LGKM(0); MM(4, afB, 1); VM0(); BAR();
    Ab = (const char*)As[1]; Bb = (const char*)Bs[1];
    LD_B(0); LD_B(1); LD_AF(afA, 0, 0); LD_AF(afB, 1, 0);
    LGKM(4); MM(0, afA, 0);
    LD_AF(afA, 0, 1);
    LGKM(4); MM(4, afB, 0);
    LD_AF(afB, 1, 1);
    LGKM(4); MM(0, afA, 1);
    LGKM(0); MM(4, afB, 1);
  }
#undef STG_A
#undef STG_B
#undef LD_B
#undef LD_AF
#undef MM
#undef BAR
#undef LGKM
#undef VM6
#undef VM0

  const float scale = 0x1p-20f;
  int rowb = bm * 256 + wm * 128 + ((lane >> 4) * 4);
  int colb = bn * 256 + wn * 64 + (lane & 15);
  float be[4];
#pragma unroll
  for (int ni = 0; ni < 4; ++ni) be[ni] = b_enc[colb + ni * 16];
#pragma unroll
  for (int mi = 0; mi < 8; ++mi)
#pragma unroll
    for (int ni = 0; ni < 4; ++ni)
#pragma unroll
      for (int r = 0; r < 4; ++r)
        h[(size_t)(rowb + mi * 16 + r) * NLAT + colb + ni * 16] =
            (half_t)(acc[mi][ni][r] * scale + be[ni]);
}

// ---------------- kernel 3a: candidate collection (pure h stream) ----------------
// Chunk-max threshold: T = 32nd-largest of 256 per-thread maxes (disjoint
// 64-elem subsets); T <= v32(stored) by pigeonhole; margin 0.02 >= 2*(GEMM
// fp16 noise + storage rounding ~7e-3) guarantees all true top-32 collected.
// Separated from the gather kernel so the 128MB h stream does not evict
// W_enc/WdT from L3 while other blocks gather.
__global__ __launch_bounds__(256) void cand_kernel(
    const half_t* __restrict__ h, int* __restrict__ candIdx,
    int* __restrict__ candCnt, int r0) {
  int rl = blockIdx.x, tid = threadIdx.x;
  int rg = r0 + rl;
  const ushort8_t* ph8 = (const ushort8_t*)(h + (size_t)rl * NLAT);

  __shared__ half_t hrow[NLAT];     // 32KB row copy
  __shared__ float tmax[256];
  __shared__ float sThresh;
  __shared__ int cCount;

  if (tid == 0) cCount = 0;
  float m = -3.4e38f;
  for (int i = 0; i < 8; ++i) {
    ushort8_t v = ph8[tid + i * 256];
    ((ushort8_t*)hrow)[tid + i * 256] = v;
#pragma unroll
    for (int e = 0; e < 8; ++e) {
      float f = (float)__builtin_bit_cast(_Float16, (unsigned short)v[e]);
      m = fmaxf(m, f);
    }
  }
  tmax[tid] = m;
  __syncthreads();
  {
    int rank = 0;
    for (int o = 0; o < 256; ++o) {
      float vo = tmax[o];
      rank += (vo > m || (vo == m && o < tid)) ? 1 : 0;
    }
    if (rank == 31) sThresh = m - 0.02f;
  }
  __syncthreads();
  float thresh = sThresh;

  for (int i = 0; i < 8; ++i) {
    ushort8_t v = ((const ushort8_t*)hrow)[tid + i * 256];
#pragma unroll
    for (int e = 0; e < 8; ++e) {
      float f = (float)__builtin_bit_cast(_Float16, (unsigned short)v[e]);
      if (f >= thresh) {
        int slot = atomicAdd(&cCount, 1);
        if (slot < CAND_MAX) candIdx[(size_t)rg * CAND_MAX + slot] = (tid + i * 256) * 8 + e;
      }
    }
  }
  __syncthreads();
  if (tid == 0) candCnt[rg] = (cCount < CAND_MAX) ? cCount : CAND_MAX;
}

// ---------------- kernel 3b: fp64 refine + rank-select + decode ----------------
// Runs after cand_kernel: no h stream competing, so W_enc (64MB) + WdT (32MB)
// stay L3-resident and the gathers are L3-hits.
__global__ __launch_bounds__(256) void refine_sel_decode(
    const float* __restrict__ x, const float* __restrict__ b_pre,
    const float* __restrict__ W_enc, const float* __restrict__ b_enc,
    const double* __restrict__ meanD, const double* __restrict__ normD,
    const int* __restrict__ candIdx, const int* __restrict__ candCnt,
    const half_t* __restrict__ WdT, float* __restrict__ out, int r0) {
  int rg = r0 + blockIdx.x, tid = threadIdx.x;
  int wv = tid >> 6, ln = tid & 63;

  __shared__ int cI[CAND_MAX];
  __shared__ double cV[CAND_MAX];
  __shared__ float sVal[32];
  __shared__ int sIdx[32];

  // fp64 normalized row fragment: lane ln owns elements {4ln+e+256s}
  double mean = meanD[rg], nrm = normD[rg];
  const float* px = x + (size_t)rg * DMODEL;
  double xr[16];
#pragma unroll
  for (int s = 0; s < 4; ++s) {
    float4 xv = *(const float4*)(px + s * 256 + 4 * ln);
    float4 bv = *(const float4*)(b_pre + s * 256 + 4 * ln);
    xr[s * 4 + 0] = ((double)xv.x - mean) / nrm - (double)bv.x;
    xr[s * 4 + 1] = ((double)xv.y - mean) / nrm - (double)bv.y;
    xr[s * 4 + 2] = ((double)xv.z - mean) / nrm - (double)bv.z;
    xr[s * 4 + 3] = ((double)xv.w - mean) / nrm - (double)bv.w;
  }
  int nc = candCnt[rg];
  for (int c = tid; c < nc; c += 256) cI[c] = candIdx[(size_t)rg * CAND_MAX + c];
  if (tid < 32) { sVal[tid] = 0.0f; sIdx[tid] = 0; }
  __syncthreads();

  // ---- exact fp64 dots; 4 waves x 4 candidates; float4 loads hoisted ----
  for (int c0 = wv * 4; c0 < nc; c0 += 16) {
    const char* wp[4];
#pragma unroll
    for (int qq = 0; qq < 4; ++qq) {
      int c = c0 + qq;
      int j = cI[c < nc ? c : (nc - 1)];
      wp[qq] = (const char*)(W_enc + (size_t)j * DMODEL) + 16 * ln;
    }
    float4 w[4][4];
#pragma unroll
    for (int s = 0; s < 4; ++s)
#pragma unroll
      for (int qq = 0; qq < 4; ++qq)
        w[s][qq] = *(const float4*)(wp[qq] + s * 1024);
    double a0 = 0.0, a1 = 0.0, a2 = 0.0, a3 = 0.0;
#pragma unroll
    for (int s = 0; s < 4; ++s) {
      a0 += xr[s*4+0]*(double)w[s][0].x + xr[s*4+1]*(double)w[s][0].y +
            xr[s*4+2]*(double)w[s][0].z + xr[s*4+3]*(double)w[s][0].w;
      a1 += xr[s*4+0]*(double)w[s][1].x + xr[s*4+1]*(double)w[s][1].y +
            xr[s*4+2]*(double)w[s][1].z + xr[s*4+3]*(double)w[s][1].w;
      a2 += xr[s*4+0]*(double)w[s][2].x + xr[s*4+1]*(double)w[s][2].y +
            xr[s*4+2]*(double)w[s][2].z + xr[s*4+3]*(double)w[s][2].w;
      a3 += xr[s*4+0]*(double)w[s][3].x + xr[s*4+1]*(double)w[s][3].y +
            xr[s*4+2]*(double)w[s][3].z + xr[s*4+3]*(double)w[s][3].w;
    }
    double accq[4] = {a0, a1, a2, a3};
#pragma unroll
    for (int qq = 0; qq < 4; ++qq) {
      double s = accq[qq];
      for (int off = 32; off; off >>= 1) s += __shfl_down(s, off);
      int c = c0 + qq;
      if (ln == 0 && c < nc) cV[c] = s + (double)b_enc[cI[c]];
    }
  }
  __syncthreads();

  // ---- rank-count exact top-32 (value desc, index asc) ----
  for (int c = tid; c < nc; c += 256) {
    double v = cV[c];
    int ix = cI[c];
    int rank = 0;
    for (int o = 0; o < nc; ++o) {
      double vo = cV[o];
      int io = cI[o];
      rank += (vo > v || (vo == v && io < ix)) ? 1 : 0;
    }
    if (rank < 32) {
      sIdx[rank] = ix;
      sVal[rank] = (float)(v > 0.0 ? v : 0.0);  // relu
    }
  }
  __syncthreads();

  // ---- sparse decode + denormalize ----
  int d0 = tid * 4;
  float4 accv = {0.f, 0.f, 0.f, 0.f};
#pragma unroll 8
  for (int k = 0; k < 32; ++k) {
    float vk = sVal[k];
    const half4_t wvv = *(const half4_t*)(WdT + (size_t)sIdx[k] * DMODEL + d0);
    accv.x += vk * (float)wvv[0]; accv.y += vk * (float)wvv[1];
    accv.z += vk * (float)wvv[2]; accv.w += vk * (float)wvv[3];
  }
  float4 bp = ((const float4*)b_pre)[tid];
  float nrmf = (float)nrm, mnf = (float)mean;
  float4 o;
  o.x = (accv.x + bp.x) * nrmf + mnf;
  o.y = (accv.y + bp.y) * nrmf + mnf;
  o.z = (accv.z + bp.z) * nrmf + mnf;
  o.w = (accv.w + bp.w) * nrmf + mnf;
  ((float4*)(out + (size_t)rg * DMODEL))[tid] = o;
}

// ---------------- launcher ----------------
extern "C" void kernel_launch(void* const* d_in, const int* in_sizes, int n_in,
                              void* d_out, int out_size, void* d_ws, size_t ws_size,
                              hipStream_t stream) {
  const float* x     = (const float*)d_in[0];
  const float* b_pre = (const float*)d_in[1];
  const float* W_enc = (const float*)d_in[2];
  const float* b_enc = (const float*)d_in[3];
  const float* W_dec = (const float*)d_in[4];
  float* out = (float*)d_out;
  char* ws = (char*)d_ws;

  int rowsB = NROWS;
  while (rowsB > 256) {
    size_t need = oBatch + (size_t)rowsB * BATCH_ROW_BYTES;
    if (need <= ws_size) break;
    rowsB >>= 1;
  }
  if (oBatch + (size_t)rowsB * BATCH_ROW_BYTES > ws_size) return;  // fail soft

  half_t* W0 = (half_t*)(ws + oW0);
  half_t* WdT = (half_t*)(ws + oWdT);
  double* meanD = (double*)(ws + oMeanD);
  double* normD = (double*)(ws + oNormD);
  int*   candCnt = (int*)(ws + oCandC);
  int*   candIdx = (int*)(ws + oCandI);
  half_t* X0b  = (half_t*)(ws + oBatch);
  half_t* hb   = X0b + (size_t)rowsB * DMODEL;

  for (int r0 = 0; r0 < NROWS; r0 += rowsB) {
    hipLaunchKernelGGL(prepro_kernel,
                       dim3(WSPLIT_B + TRANS_B + rowsB), dim3(256), 0, stream,
                       x, b_pre, W_enc, W_dec, W0, WdT, X0b, meanD, normD, r0);
    int mtiles = rowsB / 256;
    hipLaunchKernelGGL(gemm_enc, dim3(mtiles * 64), dim3(512), 0, stream,
                       X0b, W0, b_enc, hb, mtiles);
    hipLaunchKernelGGL(cand_kernel, dim3(rowsB), dim3(256), 0, stream,
                       hb, candIdx, candCnt, r0);
    hipLaunchKernelGGL(refine_sel_decode, dim3(rowsB), dim3(256), 0, stream,
                       x, b_pre, W_enc, b_enc, meanD, normD, candIdx, candCnt,
                       WdT, out, r0);
  }
}

// Round 19
// 326.825 us; speedup vs baseline: 1.0835x; 1.0835x over previous
//
#include <hip/hip_runtime.h>
#include <cstdint>
#include <cstddef>

typedef _Float16 half_t;
typedef _Float16 half4_t __attribute__((ext_vector_type(4)));
typedef _Float16 half8_t __attribute__((ext_vector_type(8)));
typedef unsigned short ushort8_t __attribute__((ext_vector_type(8)));
typedef float floatx4 __attribute__((ext_vector_type(4)));

#define NROWS 4096
#define DMODEL 1024
#define NLAT 16384
#define CAND_MAX 256

// ---------------- ws layout (bytes) ----------------
#define MBYTE (1ull << 20)
static const size_t oW0    = 0;                           // 32MB fp16 W_enc*1024
static const size_t oWdT   = 32 * MBYTE;                  // 32MB fp16 W_dec^T
static const size_t oMeanD = 64 * MBYTE;                  // 32KB
static const size_t oNormD = 64 * MBYTE + (64ull << 10);  // 32KB
static const size_t oBatch = 65 * MBYTE;

// per-row batch bytes: X0 fp16 (2048) + hb fp16 (32768)
#define BATCH_ROW_BYTES 34816ull

// ---------------- helpers ----------------
__device__ __forceinline__ void gload16(const void* g, void* l) {
  __builtin_amdgcn_global_load_lds(
      (const __attribute__((address_space(1))) void*)g,
      (__attribute__((address_space(3))) void*)l, 16, 0, 0);
}

// ---------------- kernel 1: fused preprocessing ----------------
#define WSPLIT_B 2048
#define TRANS_B  4096   // (NLAT/64) * (DMODEL/64)
__global__ __launch_bounds__(256) void prepro_kernel(
    const float* __restrict__ x, const float* __restrict__ b_pre,
    const float* __restrict__ W_enc, const float* __restrict__ Wd,
    half_t* __restrict__ W0h, half_t* __restrict__ WdT,
    half_t* __restrict__ X0,
    double* __restrict__ meanD, double* __restrict__ normD, int r0) {
  int bid = blockIdx.x, tid = threadIdx.x;
  if (bid < WSPLIT_B) {
    size_t base = (size_t)bid * 2048 + tid;
    for (int it = 0; it < 8; ++it) {
      size_t i = base + (size_t)it * 256;
      float4 v = ((const float4*)W_enc)[i];
      half4_t h0;
      h0[0] = (half_t)(v.x * 1024.0f);
      h0[1] = (half_t)(v.y * 1024.0f);
      h0[2] = (half_t)(v.z * 1024.0f);
      h0[3] = (half_t)(v.w * 1024.0f);
      ((half4_t*)W0h)[i] = h0;
    }
    return;
  }
  if (bid < WSPLIT_B + TRANS_B) {
    __shared__ float tile[64][65];
    int t = bid - WSPLIT_B;
    int c0 = (t & 255) * 64;   // over NLAT
    int r0t = (t >> 8) * 64;   // over DMODEL
    int tc = tid & 63, tg = tid >> 6;
    for (int i = 0; i < 16; ++i) {
      int rr = i * 4 + tg;
      tile[rr][tc] = Wd[(size_t)(r0t + rr) * NLAT + c0 + tc];
    }
    __syncthreads();
    for (int i = 0; i < 16; ++i) {
      int cc = i * 4 + tg;
      WdT[(size_t)(c0 + cc) * DMODEL + r0t + tc] = (half_t)tile[tc][cc];
    }
    return;
  }
  int rl = bid - WSPLIT_B - TRANS_B;
  int rg = r0 + rl;
  const float4* px = (const float4*)(x + (size_t)rg * DMODEL);
  float4 v = px[tid];
  double s  = (double)v.x + (double)v.y + (double)v.z + (double)v.w;
  double sq = (double)v.x * v.x + (double)v.y * v.y +
              (double)v.z * v.z + (double)v.w * v.w;
  for (int off = 32; off; off >>= 1) {
    s += __shfl_down(s, off);
    sq += __shfl_down(sq, off);
  }
  __shared__ double ss[4], ssq[4];
  __shared__ double sMean, sNorm;
  int wv = tid >> 6, ln = tid & 63;
  if (ln == 0) { ss[wv] = s; ssq[wv] = sq; }
  __syncthreads();
  if (tid == 0) {
    double S = ss[0] + ss[1] + ss[2] + ss[3];
    double Q = ssq[0] + ssq[1] + ssq[2] + ssq[3];
    double mean = S / (double)DMODEL;
    double var = (Q - (double)DMODEL * mean * mean) / (double)(DMODEL - 1);
    double nrm = sqrt(var) + 1e-6;
    sMean = mean; sNorm = nrm;
    meanD[rg] = mean; normD[rg] = nrm;
  }
  __syncthreads();
  float mean = (float)sMean, nrm = (float)sNorm;
  const float4* pb = (const float4*)b_pre;
  float4 bp = pb[tid];
  float c[4];
  c[0] = ((v.x - mean) / nrm - bp.x) * 1024.0f;
  c[1] = ((v.y - mean) / nrm - bp.y) * 1024.0f;
  c[2] = ((v.z - mean) / nrm - bp.z) * 1024.0f;
  c[3] = ((v.w - mean) / nrm - bp.w) * 1024.0f;
  half4_t h0;
  for (int i = 0; i < 4; ++i) h0[i] = (half_t)c[i];
  ((half4_t*)(X0 + (size_t)rl * DMODEL))[tid] = h0;
}

// ---------------- kernel 2: encode GEMM, 8-phase + coalesced LDS-bounce epilogue ----------------
struct SmemAB { half_t A[2][256 * 64]; half_t B[2][256 * 64]; };
union SmemU { SmemAB ab; half_t c[256 * 256]; };  // 128KB either way

__global__ __launch_bounds__(512, 2) void gemm_enc(
    const half_t* __restrict__ X0, const half_t* __restrict__ W0,
    const float* __restrict__ b_enc, half_t* __restrict__ h, int mtiles) {
  __shared__ __align__(16) SmemU smem;
#define AS(b) (smem.ab.A[b])
#define BS(b) (smem.ab.B[b])
  int tid = threadIdx.x;
  int lane = tid & 63, wave = tid >> 6;
  int wm = wave >> 2, wn = wave & 3;

  int bid = blockIdx.x;
  int xcd = bid & 7, q = bid >> 3;
  int bn = xcd * 8 + (q & 7);
  int bm = q >> 3;
  (void)mtiles;

  const char* Ag = (const char*)(X0 + (size_t)bm * 256 * DMODEL);
  const char* Bg = (const char*)(W0 + (size_t)bn * 256 * DMODEL);

  int srcSwz = ((lane & 7) ^ (lane >> 3)) << 4;
  int rowBase = wave * 8 + (lane >> 3);
  int ldsWOff = wave * 1024;

#define STG_A(b, kt, pr) { int colB = ((kt) & 15) * 128 + srcSwz;             \
    gload16(Ag + (size_t)((pr) * 64 + rowBase) * 2048 + colB,                 \
            (char*)AS(b) + (pr) * 8192 + ldsWOff);                            \
    gload16(Ag + (size_t)(((pr) + 2) * 64 + rowBase) * 2048 + colB,           \
            (char*)AS(b) + ((pr) + 2) * 8192 + ldsWOff); }
#define STG_B(b, kt, pr) { int colB = ((kt) & 15) * 128 + srcSwz;             \
    gload16(Bg + (size_t)((pr) * 64 + rowBase) * 2048 + colB,                 \
            (char*)BS(b) + (pr) * 8192 + ldsWOff);                            \
    gload16(Bg + (size_t)(((pr) + 2) * 64 + rowBase) * 2048 + colB,           \
            (char*)BS(b) + ((pr) + 2) * 8192 + ldsWOff); }

  floatx4 acc[8][4] = {};

  STG_B(0, 0, 0); STG_B(0, 0, 1); STG_A(0, 0, 0); STG_A(0, 0, 1);
  STG_B(1, 1, 0); STG_B(1, 1, 1); STG_A(1, 1, 0);
  asm volatile("s_waitcnt vmcnt(6)" ::: "memory");
  __builtin_amdgcn_sched_barrier(0);
  __builtin_amdgcn_s_barrier();

  int laneQ = (lane & 15) * 128 + (lane >> 4) * 16;
  int sxor = (lane & 7) << 4;
  int aRow = wm * 128 * 128;
  int bRow = wn * 64 * 128;

  half8_t bfr[2][4], afA[4], afB[4];
  const char *Ab, *Bb;

#define LD_B(kk) _Pragma("unroll") for (int t = 0; t < 4; ++t)                \
    bfr[kk][t] = *(const half8_t*)(Bb + ((bRow + t * 2048 +                   \
                                          (kk) * 64 + laneQ) ^ sxor));
#define LD_AF(DST, mh, kk) _Pragma("unroll") for (int t = 0; t < 4; ++t)      \
    DST[t] = *(const half8_t*)(Ab + ((aRow + ((mh) * 4 + t) * 2048 +          \
                                      (kk) * 64 + laneQ) ^ sxor));
#define MM(mb, FR, kk) __builtin_amdgcn_s_setprio(1);                         \
    _Pragma("unroll") for (int mi = 0; mi < 4; ++mi)                          \
    _Pragma("unroll") for (int ni = 0; ni < 4; ++ni)                          \
      acc[(mb) + mi][ni] = __builtin_amdgcn_mfma_f32_16x16x32_f16(            \
          FR[mi], bfr[kk][ni], acc[(mb) + mi][ni], 0, 0, 0);                  \
    __builtin_amdgcn_s_setprio(0);
#define BAR() __builtin_amdgcn_s_barrier()
#define LGKM(n) { asm volatile("s_waitcnt lgkmcnt(" #n ")" ::: "memory");     \
    __builtin_amdgcn_sched_barrier(0); }
#define VM6() { asm volatile("s_waitcnt vmcnt(6)" ::: "memory");              \
    __builtin_amdgcn_sched_barrier(0); }
#define VM0() { asm volatile("s_waitcnt vmcnt(0)" ::: "memory");              \
    __builtin_amdgcn_sched_barrier(0); }

#pragma unroll 1
  for (int i = 0; i < 7; ++i) {
    int t0 = 2 * i;
    Ab = (const char*)AS(0); Bb = (const char*)BS(0);
    LD_B(0); LD_B(1); LD_AF(afA, 0, 0); LD_AF(afB, 1, 0);
    STG_A(1, t0 + 1, 1);
    BAR(); LGKM(4); MM(0, afA, 0); BAR();
    LD_AF(afA, 0, 1);
    STG_B(0, t0 + 2, 0);
    BAR(); LGKM(4); MM(4, afB, 0); BAR();
    LD_AF(afB, 1, 1);
    STG_B(0, t0 + 2, 1);
    BAR(); LGKM(4); MM(0, afA, 1); BAR();
    STG_A(0, t0 + 2, 0);
    BAR(); LGKM(0); MM(4, afB, 1); VM6(); BAR();
    Ab = (const char*)AS(1); Bb = (const char*)BS(1);
    LD_B(0); LD_B(1); LD_AF(afA, 0, 0); LD_AF(afB, 1, 0);
    STG_A(0, t0 + 2, 1);
    BAR(); LGKM(4); MM(0, afA, 0); BAR();
    LD_AF(afA, 0, 1);
    STG_B(1, t0 + 3, 0);
    BAR(); LGKM(4); MM(4, afB, 0); BAR();
    LD_AF(afB, 1, 1);
    STG_B(1, t0 + 3, 1);
    BAR(); LGKM(4); MM(0, afA, 1); BAR();
    STG_A(1, t0 + 3, 0);
    BAR(); LGKM(0); MM(4, afB, 1); VM6(); BAR();
  }
  {
    Ab = (const char*)AS(0); Bb = (const char*)BS(0);
    LD_B(0); LD_B(1); LD_AF(afA, 0, 0); LD_AF(afB, 1, 0);
    STG_A(1, 15, 1);
    BAR(); LGKM(4); MM(0, afA, 0); BAR();
    LD_AF(afA, 0, 1);
    BAR(); LGKM(4); MM(4, afB, 0); BAR();
    LD_AF(afB, 1, 1);
    BAR(); LGKM(4); MM(0, afA, 1); BAR();
    BAR(); LGKM(0); MM(4, afB, 1); VM0(); BAR();
    Ab = (const char*)AS(1); Bb = (const char*)BS(1);
    LD_B(0); LD_B(1); LD_AF(afA, 0, 0); LD_AF(afB, 1, 0);
    LGKM(4); MM(0, afA, 0);
    LD_AF(afA, 0, 1);
    LGKM(4); MM(4, afB, 0);
    LD_AF(afB, 1, 1);
    LGKM(4); MM(0, afA, 1);
    LGKM(0); MM(4, afB, 1);
  }
#undef STG_A
#undef STG_B
#undef LD_B
#undef LD_AF
#undef MM
#undef BAR
#undef LGKM
#undef VM6
#undef VM0

  // ---- epilogue: C tile -> LDS (XOR-swizzled 16B blocks) -> coalesced stores ----
  __syncthreads();   // all waves done reading As/Bs; LDS now reusable as C tile
  const float scale = 0x1p-20f;
  half_t* Cs = smem.c;
  {
    int lcBase = wn * 64 + (lane & 15);
    int lrBase = wm * 128 + (lane >> 4) * 4;
    float be[4];
#pragma unroll
    for (int ni = 0; ni < 4; ++ni) be[ni] = b_enc[bn * 256 + lcBase + ni * 16];
#pragma unroll
    for (int mi = 0; mi < 8; ++mi)
#pragma unroll
      for (int ni = 0; ni < 4; ++ni) {
        int lc = lcBase + ni * 16;
#pragma unroll
        for (int r = 0; r < 4; ++r) {
          int lr = lrBase + mi * 16 + r;
          half_t val = (half_t)(acc[mi][ni][r] * scale + be[ni]);
          int addr = lr * 512 + (((lc >> 3) ^ (lr & 15)) << 4) + ((lc & 7) << 1);
          *(half_t*)((char*)Cs + addr) = val;
        }
      }
  }
  __syncthreads();
  {
    // wave handles rows [wave*32, wave*32+32): per iter 2 rows x 512B contiguous
    int blk = lane & 31;
    int rsub = lane >> 5;                 // 0/1
#pragma unroll
    for (int j = 0; j < 16; ++j) {
      int row = wave * 32 + j * 2 + rsub;
      int laddr = row * 512 + ((blk ^ (row & 15)) << 4);
      half8_t v = *(const half8_t*)((const char*)Cs + laddr);
      *(half8_t*)(h + (size_t)(bm * 256 + row) * NLAT + bn * 256 + blk * 8) = v;
    }
  }
#undef AS
#undef BS
}

// ---------------- kernel 3: fused postprocessing (R13 structure: chunk-max + hrow) ----------------
// Threshold: T = 32nd-largest of 256 per-thread maxes (disjoint 64-elem subsets).
// T <= v32(stored) by pigeonhole; margin 0.02 >= 2*(GEMM fp16 noise + storage
// rounding ~7e-3) guarantees every true top-32 index is collected.
__global__ __launch_bounds__(256) void postproc(
    const half_t* __restrict__ h, const float* __restrict__ x,
    const float* __restrict__ b_pre, const float* __restrict__ W_enc,
    const float* __restrict__ b_enc,
    const double* __restrict__ meanD, const double* __restrict__ normD,
    const half_t* __restrict__ WdT, float* __restrict__ out, int r0) {
  int rl = blockIdx.x, tid = threadIdx.x;
  int rg = r0 + rl;
  int wv = tid >> 6, ln = tid & 63;
  const ushort8_t* ph8 = (const ushort8_t*)(h + (size_t)rl * NLAT);

  __shared__ half_t hrow[NLAT];     // 32KB row copy
  __shared__ float tmax[256];
  __shared__ float sThresh;
  __shared__ int cCount;
  __shared__ int cI[CAND_MAX];
  __shared__ double cV[CAND_MAX];
  __shared__ float sVal[32];
  __shared__ int sIdx[32];

  // fp64 normalized row fragment, register-resident
  double mean = meanD[rg], nrm = normD[rg];
  const float* px = x + (size_t)rg * DMODEL;
  double xr[16];
#pragma unroll
  for (int u = 0; u < 16; ++u)
    xr[u] = ((double)px[ln + u * 64] - mean) / nrm - (double)b_pre[ln + u * 64];

  // ---- phase A: copy row to LDS + per-thread max over 64 disjoint values ----
  if (tid == 0) cCount = 0;
  float m = -3.4e38f;
  for (int i = 0; i < 8; ++i) {
    ushort8_t v = ph8[tid + i * 256];
    ((ushort8_t*)hrow)[tid + i * 256] = v;
#pragma unroll
    for (int e = 0; e < 8; ++e) {
      float f = (float)__builtin_bit_cast(_Float16, (unsigned short)v[e]);
      m = fmaxf(m, f);
    }
  }
  tmax[tid] = m;
  __syncthreads();

  // ---- phase A': T = 32nd-largest per-thread max (lexicographic rank) ----
  {
    int rank = 0;
    for (int o = 0; o < 256; ++o) {
      float vo = tmax[o];
      rank += (vo > m || (vo == m && o < tid)) ? 1 : 0;
    }
    if (rank == 31) sThresh = m - 0.02f;
  }
  __syncthreads();
  float thresh = sThresh;

  // ---- phase B: collect candidate indices from the LDS row ----
  for (int i = 0; i < 8; ++i) {
    ushort8_t v = ((const ushort8_t*)hrow)[tid + i * 256];
#pragma unroll
    for (int e = 0; e < 8; ++e) {
      float f = (float)__builtin_bit_cast(_Float16, (unsigned short)v[e]);
      if (f >= thresh) {
        int slot = atomicAdd(&cCount, 1);
        if (slot < CAND_MAX) cI[slot] = (tid + i * 256) * 8 + e;
      }
    }
  }
  __syncthreads();
  int nc = (cCount < CAND_MAX) ? cCount : CAND_MAX;

  // ---- phase C: exact fp64 dots, 4 waves x 4 candidates, 4-way ILP ----
  for (int c0 = wv * 4; c0 < nc; c0 += 16) {
    const float* wp[4];
#pragma unroll
    for (int qq = 0; qq < 4; ++qq) {
      int c = c0 + qq;
      int j = cI[c < nc ? c : (nc - 1)];
      wp[qq] = W_enc + (size_t)j * DMODEL + ln;
    }
    double a0 = 0.0, a1 = 0.0, a2 = 0.0, a3 = 0.0;
#pragma unroll
    for (int u = 0; u < 16; ++u) {
      float w0 = wp[0][u * 64];
      float w1 = wp[1][u * 64];
      float w2 = wp[2][u * 64];
      float w3 = wp[3][u * 64];
      a0 += xr[u] * (double)w0;
      a1 += xr[u] * (double)w1;
      a2 += xr[u] * (double)w2;
      a3 += xr[u] * (double)w3;
    }
    double accq[4] = {a0, a1, a2, a3};
#pragma unroll
    for (int qq = 0; qq < 4; ++qq) {
      double s = accq[qq];
      for (int off = 32; off; off >>= 1) s += __shfl_down(s, off);
      int c = c0 + qq;
      if (ln == 0 && c < nc) cV[c] = s + (double)b_enc[cI[c]];
    }
  }
  if (tid < 32) { sVal[tid] = 0.0f; sIdx[tid] = 0; }
  __syncthreads();

  // ---- phase D: rank-count exact top-32 (value desc, index asc) ----
  for (int c = tid; c < nc; c += 256) {
    double v = cV[c];
    int ix = cI[c];
    int rank = 0;
    for (int o = 0; o < nc; ++o) {
      double vo = cV[o];
      int io = cI[o];
      rank += (vo > v || (vo == v && io < ix)) ? 1 : 0;
    }
    if (rank < 32) {
      sIdx[rank] = ix;
      sVal[rank] = (float)(v > 0.0 ? v : 0.0);  // relu
    }
  }
  __syncthreads();

  // ---- phase E: sparse decode + denormalize ----
  int d0 = tid * 4;
  float4 accv = {0.f, 0.f, 0.f, 0.f};
#pragma unroll 8
  for (int k = 0; k < 32; ++k) {
    float vk = sVal[k];
    const half4_t wvv = *(const half4_t*)(WdT + (size_t)sIdx[k] * DMODEL + d0);
    accv.x += vk * (float)wvv[0]; accv.y += vk * (float)wvv[1];
    accv.z += vk * (float)wvv[2]; accv.w += vk * (float)wvv[3];
  }
  float4 bp = ((const float4*)b_pre)[tid];
  float nrmf = (float)nrm, mnf = (float)mean;
  float4 o;
  o.x = (accv.x + bp.x) * nrmf + mnf;
  o.y = (accv.y + bp.y) * nrmf + mnf;
  o.z = (accv.z + bp.z) * nrmf + mnf;
  o.w = (accv.w + bp.w) * nrmf + mnf;
  ((float4*)(out + (size_t)rg * DMODEL))[tid] = o;
}

// ---------------- launcher ----------------
extern "C" void kernel_launch(void* const* d_in, const int* in_sizes, int n_in,
                              void* d_out, int out_size, void* d_ws, size_t ws_size,
                              hipStream_t stream) {
  const float* x     = (const float*)d_in[0];
  const float* b_pre = (const float*)d_in[1];
  const float* W_enc = (const float*)d_in[2];
  const float* b_enc = (const float*)d_in[3];
  const float* W_dec = (const float*)d_in[4];
  float* out = (float*)d_out;
  char* ws = (char*)d_ws;

  int rowsB = NROWS;
  while (rowsB > 256) {
    size_t need = oBatch + (size_t)rowsB * BATCH_ROW_BYTES;
    if (need <= ws_size) break;
    rowsB >>= 1;
  }
  if (oBatch + (size_t)rowsB * BATCH_ROW_BYTES > ws_size) return;  // fail soft

  half_t* W0 = (half_t*)(ws + oW0);
  half_t* WdT = (half_t*)(ws + oWdT);
  double* meanD = (double*)(ws + oMeanD);
  double* normD = (double*)(ws + oNormD);
  half_t* X0b  = (half_t*)(ws + oBatch);
  half_t* hb   = X0b + (size_t)rowsB * DMODEL;

  for (int r0 = 0; r0 < NROWS; r0 += rowsB) {
    hipLaunchKernelGGL(prepro_kernel,
                       dim3(WSPLIT_B + TRANS_B + rowsB), dim3(256), 0, stream,
                       x, b_pre, W_enc, W_dec, W0, WdT, X0b, meanD, normD, r0);
    int mtiles = rowsB / 256;
    hipLaunchKernelGGL(gemm_enc, dim3(mtiles * 64), dim3(512), 0, stream,
                       X0b, W0, b_enc, hb, mtiles);
    hipLaunchKernelGGL(postproc, dim3(rowsB), dim3(256), 0, stream,
                       hb, x, b_pre, W_enc, b_enc, meanD, normD, WdT, out, r0);
  }
}